// Round 6
// baseline (138.860 us; speedup 1.0000x reference)
//
#include <hip/hip_runtime.h>
#include <hip/hip_bf16.h>

typedef __attribute__((ext_vector_type(8))) short  short8;
typedef __attribute__((ext_vector_type(8))) unsigned short ushort8;
typedef __attribute__((ext_vector_type(4))) unsigned short usv4;
typedef __attribute__((ext_vector_type(4))) float  f32x4;

#define D_DIM 1152
#define O_DIM 256
#define N_TOT 100352
#define XT_H 58
#define XT_ROW (58 * 128)

__device__ __forceinline__ unsigned short f2bf(float f) {
  __hip_bfloat16 h = __float2bfloat16(f);
  return __builtin_bit_cast(unsigned short, h);
}

#define GLOAD_LDS16(g, l)                                              \
  __builtin_amdgcn_global_load_lds(                                    \
      (const __attribute__((address_space(1))) void*)(g),              \
      (__attribute__((address_space(3))) void*)(l), 16, 0, 0)

// ---------------------------------------------------------------------------
// Kernel 1: Wt[o][dn] via LDS-tiled fp32 block-GEMM (proven R4)
// ---------------------------------------------------------------------------
__global__ __launch_bounds__(256) void wt_kernel(
    const float* __restrict__ S1s, const float* __restrict__ U1s,
    const float* __restrict__ U2s, const float* __restrict__ S2s,
    unsigned short* __restrict__ Wt) {
  __shared__ float A_lds[32][64];
  __shared__ float B_lds[32][64];

  const int bo = blockIdx.x & 3;
  const int bd = blockIdx.x >> 2;
  const int o0  = bo << 6;
  const int dn0 = bd << 6;
  const int rr  = dn0 >> 7;
  const int c0  = dn0 & 127;

  const int tid = threadIdx.x;
  const int ty = tid >> 4, tx = tid & 15;

  float acc[4][4] = {};

  for (int kc = 0; kc < 15; ++kc) {
#pragma unroll
    for (int e = 0; e < 8; ++e) {
      const int li = e * 256 + tid;
      const int kk = li >> 6;
      const int xx = li & 63;
      const int k  = kc * 32 + kk;
      float av, bv;
      if (k < 48) {
        av = U1s[k * O_DIM + o0 + xx];
        const int d_old = (c0 + xx) * 9 + rr;
        bv = S1s[(size_t)((k >> 3) * D_DIM + d_old) * 8 + (k & 7)];
      } else {
        const int kq = k - 48;
        av = S2s[(size_t)kq * O_DIM + o0 + xx];
        const int d_old = (c0 + xx) * 9 + rr;
        bv = U2s[(size_t)kq * D_DIM + d_old];
      }
      A_lds[kk][xx] = av;
      B_lds[kk][xx] = bv;
    }
    __syncthreads();
#pragma unroll
    for (int kk = 0; kk < 32; ++kk) {
      f32x4 a = *(const f32x4*)&A_lds[kk][ty << 2];
      f32x4 b = *(const f32x4*)&B_lds[kk][tx << 2];
#pragma unroll
      for (int i = 0; i < 4; ++i)
#pragma unroll
        for (int j = 0; j < 4; ++j)
          acc[i][j] += a[i] * b[j];
    }
    __syncthreads();
  }

#pragma unroll
  for (int i = 0; i < 4; ++i) {
    usv4 v;
#pragma unroll
    for (int j = 0; j < 4; ++j) v[j] = f2bf(acc[i][j] * (1.0f / 6.0f));
    *(usv4*)(Wt + (size_t)(o0 + (ty << 2) + i) * D_DIM + dn0 + (tx << 2)) = v;
  }
}

// ---------------------------------------------------------------------------
// Kernel 2: pad+transpose x[B,C,H,W] fp32 -> x_t[b][ih][iw][c] bf16 (proven R4)
// ---------------------------------------------------------------------------
__global__ __launch_bounds__(256) void pad_kernel(const float* __restrict__ x,
                                                  unsigned short* __restrict__ xt) {
  int blk = blockIdx.x;
  int b = blk / XT_H, ih = blk - b * XT_H;
  unsigned short* dst = xt + (size_t)blk * XT_ROW;
  int tid = threadIdx.x;

  if (ih == 0 || ih == XT_H - 1) {
    ushort8 z;
#pragma unroll
    for (int q = 0; q < 8; ++q) z[q] = 0;
    for (int i = tid; i < XT_ROW / 8; i += 256) ((ushort8*)dst)[i] = z;
    return;
  }

  __shared__ unsigned short lds[128 * 58];
  int h = ih - 1;
  const float* xb = x + (size_t)b * 128 * 3136 + (size_t)h * 56;
#pragma unroll 4
  for (int r = 0; r < 28; ++r) {
    int idx = r * 256 + tid;
    int c = idx / 56, w2 = idx - c * 56;
    lds[c * 58 + w2] = f2bf(xb[(size_t)c * 3136 + w2]);
  }
  __syncthreads();
#pragma unroll 4
  for (int r = 0; r < 29; ++r) {
    int idx = r * 256 + tid;
    int iw = idx >> 7, c = idx & 127;
    unsigned short v = 0;
    if (iw >= 1 && iw <= 56) v = lds[c * 58 + (iw - 1)];
    dst[idx] = v;
  }
}

// ---------------------------------------------------------------------------
// Kernel 3: implicit-im2col GEMM, phased schedule (T2+T3+T4+T5).
// BM=128(o) x BN=256(n), BK=64, 8 waves (2M x 4N), wave tile 64x64.
// 3 LDS slots (48KB each): slot kt%3; stage kt+2 during kt; vmcnt(6) at
// K-tile end keeps this tile's 6 staging loads in flight across the barrier.
// st_16x32 swizzle: linear LDS dest + pre-swizzled global source + swizzled
// ds_read (involution: byte ^= ((row>>2)&1)<<5, i.e. 16B-group ^= 2).
// ---------------------------------------------------------------------------
__device__ __forceinline__ constexpr int KB_OFF(int kt) {
  // xt element offset for K-tile kt: (kh*58+kw)*128 + (kt&1)*64
  int rr = kt >> 1;
  return ((rr / 3) * 58 + (rr % 3)) * 128 + (kt & 1) * 64;
}

#define ST_A(kts, sl2, r) \
  GLOAD_LDS16(pA[r] + (kts) * 64, smem + (sl2) * 24576 + (r) * 4096 + (w << 9))
#define ST_B(kts, sl2, r) \
  GLOAD_LDS16(pB[r] + KB_OFF(kts), smem + (sl2) * 24576 + 8192 + (r) * 4096 + (w << 9))

#define LDS_FRAG(base, row, ks)                                            \
  (*(const short8*)((const char*)(base) +                                  \
     ((((row) * 128) + (ks) * 64 + ((lane >> 4) << 4)) ^ ((((row) >> 2) & 1) << 5))))

__global__ __launch_bounds__(512, 2) void gemm_kernel(
    const unsigned short* __restrict__ Wt, const unsigned short* __restrict__ xt,
    const float* __restrict__ bias, float* __restrict__ out) {
  __shared__ __align__(1024) unsigned short smem[3 * 24576];  // 144 KiB

  // XCD swizzle (784 % 8 == 0): pair the 2 o-tiles of each n-tile on one XCD
  const int bid   = blockIdx.x;
  const int lid   = (bid & 7) * 98 + (bid >> 3);
  const int ntile = lid >> 1, otile = lid & 1;
  const int n0 = ntile << 8;   // *256
  const int o0 = otile << 7;   // *128

  const int tid  = threadIdx.x;
  const int w    = tid >> 6;
  const int lane = tid & 63;
  const int wm   = w >> 2;     // 0..1  (o)
  const int wn   = w & 3;      // 0..3  (n)

  // ---- staging source pointers (per-thread, fixed; pre-swizzled group) ----
  const unsigned short* pA[2];
  const unsigned short* pB[4];
#pragma unroll
  for (int r = 0; r < 2; ++r) {
    const int li  = r * 512 + tid;
    const int row = li >> 3;
    const int gs  = (li & 7) ^ (((row >> 2) & 1) << 1);
    pA[r] = Wt + (size_t)(o0 + row) * D_DIM + gs * 8;
  }
#pragma unroll
  for (int r = 0; r < 4; ++r) {
    const int li  = r * 512 + tid;
    const int row = li >> 3;
    const int gs  = (li & 7) ^ (((row >> 2) & 1) << 1);
    const int n_g = n0 + row;
    const int b   = n_g / 3136;
    const int s   = n_g - b * 3136;
    const int oh  = s / 56, ow = s - oh * 56;
    pB[r] = xt + (((size_t)b * XT_H + oh) * XT_H + ow) * 128 + gs * 8;
  }

  f32x4 acc[4][4] = {};

  // ---- prologue: stage K-tiles 0,1 into slots 0,1 ----
  ST_A(0, 0, 0); ST_A(0, 0, 1);
  ST_B(0, 0, 0); ST_B(0, 0, 1); ST_B(0, 0, 2); ST_B(0, 0, 3);
  ST_A(1, 1, 0); ST_A(1, 1, 1);
  ST_B(1, 1, 0); ST_B(1, 1, 1); ST_B(1, 1, 2); ST_B(1, 1, 3);
  asm volatile("s_waitcnt vmcnt(6)" ::: "memory");   // K-tile 0 landed
  __builtin_amdgcn_s_barrier();

#pragma unroll
  for (int kt = 0; kt < 18; ++kt) {
    const int sl  = kt % 3;
    const int kts = kt + 2;
    const int sl2 = kts % 3;
    const unsigned short* As = smem + sl * 24576;
    const unsigned short* Bs = smem + sl * 24576 + 8192;

    short8 af[4][2], bf[2][2], bf2[2][2];

    // ---------- phase 0: frags (A all, B n0-1) + stage 3, MFMA n-quad 0 ----
#pragma unroll
    for (int mi = 0; mi < 4; ++mi) {
      const int row = (wm << 6) + (mi << 4) + (lane & 15);
      af[mi][0] = LDS_FRAG(As, row, 0);
      af[mi][1] = LDS_FRAG(As, row, 1);
    }
#pragma unroll
    for (int ni = 0; ni < 2; ++ni) {
      const int row = (wn << 6) + (ni << 4) + (lane & 15);
      bf[ni][0] = LDS_FRAG(Bs, row, 0);
      bf[ni][1] = LDS_FRAG(Bs, row, 1);
    }
    if (kts < 18) { ST_A(kts, sl2, 0); ST_A(kts, sl2, 1); ST_B(kts, sl2, 0); }
    __builtin_amdgcn_s_barrier();
    __builtin_amdgcn_s_setprio(1);
#pragma unroll
    for (int mi = 0; mi < 4; ++mi)
#pragma unroll
      for (int ni = 0; ni < 2; ++ni)
#pragma unroll
        for (int ks = 0; ks < 2; ++ks)
          acc[mi][ni] = __builtin_amdgcn_mfma_f32_16x16x32_bf16(
              af[mi][ks], bf[ni][ks], acc[mi][ni], 0, 0, 0);
    __builtin_amdgcn_s_setprio(0);
    __builtin_amdgcn_s_barrier();

    // ---------- phase 1: frags (B n2-3) + stage 3, MFMA n-quad 1 ----------
#pragma unroll
    for (int ni = 0; ni < 2; ++ni) {
      const int row = (wn << 6) + ((ni + 2) << 4) + (lane & 15);
      bf2[ni][0] = LDS_FRAG(Bs, row, 0);
      bf2[ni][1] = LDS_FRAG(Bs, row, 1);
    }
    if (kts < 18) { ST_B(kts, sl2, 1); ST_B(kts, sl2, 2); ST_B(kts, sl2, 3); }
    __builtin_amdgcn_s_barrier();
    __builtin_amdgcn_s_setprio(1);
#pragma unroll
    for (int mi = 0; mi < 4; ++mi)
#pragma unroll
      for (int ni = 0; ni < 2; ++ni)
#pragma unroll
        for (int ks = 0; ks < 2; ++ks)
          acc[mi][2 + ni] = __builtin_amdgcn_mfma_f32_16x16x32_bf16(
              af[mi][ks], bf2[ni][ks], acc[mi][2 + ni], 0, 0, 0);
    __builtin_amdgcn_s_setprio(0);
    if (kt < 16) asm volatile("s_waitcnt vmcnt(6)" ::: "memory");
    else         asm volatile("s_waitcnt vmcnt(0)" ::: "memory");
    __builtin_amdgcn_s_barrier();
  }

  // ---- epilogue: D row = o (lane>>4)*4+reg, col = n (lane&15) ----
  const int lr = (lane >> 4) << 2;
  const int lc = lane & 15;
#pragma unroll
  for (int ni = 0; ni < 4; ++ni) {
    const int ng = n0 + (wn << 6) + (ni << 4) + lc;
    const int b  = ng / 3136;
    const int s  = ng - b * 3136;
    float* op = out + (size_t)b * (O_DIM * 3136) + s;
#pragma unroll
    for (int mi = 0; mi < 4; ++mi) {
      const int og = o0 + (wm << 6) + (mi << 4) + lr;
#pragma unroll
      for (int r = 0; r < 4; ++r)
        op[(size_t)(og + r) * 3136] = acc[mi][ni][r] + 2.0f * bias[og + r];
    }
  }
}

// ---------------------------------------------------------------------------
extern "C" void kernel_launch(void* const* d_in, const int* in_sizes, int n_in,
                              void* d_out, int out_size, void* d_ws, size_t ws_size,
                              hipStream_t stream) {
  const float* x    = (const float*)d_in[0];
  const float* S1s  = (const float*)d_in[1];
  const float* U1s  = (const float*)d_in[2];
  const float* U2s  = (const float*)d_in[3];
  const float* S2s  = (const float*)d_in[4];
  const float* bias = (const float*)d_in[5];
  float* out = (float*)d_out;
  (void)ws_size;

  unsigned short* xt = (unsigned short*)d_ws;
  unsigned short* Wt = (unsigned short*)((char*)d_ws + (size_t)32 * XT_H * XT_ROW * 2);

  pad_kernel<<<dim3(32 * XT_H), dim3(256), 0, stream>>>(x, xt);
  wt_kernel<<<dim3(72), dim3(256), 0, stream>>>(S1s, U1s, U2s, S2s, Wt);
  gemm_kernel<<<dim3(784), dim3(512), 0, stream>>>(Wt, xt, bias, out);
}

// Round 7
// 126.383 us; speedup vs baseline: 1.0987x; 1.0987x over previous
//
#include <hip/hip_runtime.h>
#include <hip/hip_bf16.h>

typedef __attribute__((ext_vector_type(8))) short  short8;
typedef __attribute__((ext_vector_type(8))) unsigned short ushort8;
typedef __attribute__((ext_vector_type(4))) unsigned short usv4;
typedef __attribute__((ext_vector_type(4))) float  f32x4;

#define D_DIM 1152
#define O_DIM 256
#define N_TOT 100352
#define XT_H 58
#define XT_ROW (58 * 128)

__device__ __forceinline__ unsigned short f2bf(float f) {
  __hip_bfloat16 h = __float2bfloat16(f);
  return __builtin_bit_cast(unsigned short, h);
}

#define GLOAD_LDS16(g, l)                                              \
  __builtin_amdgcn_global_load_lds(                                    \
      (const __attribute__((address_space(1))) void*)(g),              \
      (__attribute__((address_space(3))) void*)(l), 16, 0, 0)

// ---------------------------------------------------------------------------
// Kernel 1: Wt[o][dn] via LDS-tiled fp32 block-GEMM (proven R4)
// ---------------------------------------------------------------------------
__global__ __launch_bounds__(256) void wt_kernel(
    const float* __restrict__ S1s, const float* __restrict__ U1s,
    const float* __restrict__ U2s, const float* __restrict__ S2s,
    unsigned short* __restrict__ Wt) {
  __shared__ float A_lds[32][64];
  __shared__ float B_lds[32][64];

  const int bo = blockIdx.x & 3;
  const int bd = blockIdx.x >> 2;
  const int o0  = bo << 6;
  const int dn0 = bd << 6;
  const int rr  = dn0 >> 7;
  const int c0  = dn0 & 127;

  const int tid = threadIdx.x;
  const int ty = tid >> 4, tx = tid & 15;

  float acc[4][4] = {};

  for (int kc = 0; kc < 15; ++kc) {
#pragma unroll
    for (int e = 0; e < 8; ++e) {
      const int li = e * 256 + tid;
      const int kk = li >> 6;
      const int xx = li & 63;
      const int k  = kc * 32 + kk;
      float av, bv;
      if (k < 48) {
        av = U1s[k * O_DIM + o0 + xx];
        const int d_old = (c0 + xx) * 9 + rr;
        bv = S1s[(size_t)((k >> 3) * D_DIM + d_old) * 8 + (k & 7)];
      } else {
        const int kq = k - 48;
        av = S2s[(size_t)kq * O_DIM + o0 + xx];
        const int d_old = (c0 + xx) * 9 + rr;
        bv = U2s[(size_t)kq * D_DIM + d_old];
      }
      A_lds[kk][xx] = av;
      B_lds[kk][xx] = bv;
    }
    __syncthreads();
#pragma unroll
    for (int kk = 0; kk < 32; ++kk) {
      f32x4 a = *(const f32x4*)&A_lds[kk][ty << 2];
      f32x4 b = *(const f32x4*)&B_lds[kk][tx << 2];
#pragma unroll
      for (int i = 0; i < 4; ++i)
#pragma unroll
        for (int j = 0; j < 4; ++j)
          acc[i][j] += a[i] * b[j];
    }
    __syncthreads();
  }

#pragma unroll
  for (int i = 0; i < 4; ++i) {
    usv4 v;
#pragma unroll
    for (int j = 0; j < 4; ++j) v[j] = f2bf(acc[i][j] * (1.0f / 6.0f));
    *(usv4*)(Wt + (size_t)(o0 + (ty << 2) + i) * D_DIM + dn0 + (tx << 2)) = v;
  }
}

// ---------------------------------------------------------------------------
// Kernel 2: pad+transpose x[B,C,H,W] fp32 -> x_t[b][ih][iw][c] bf16 (proven R4)
// ---------------------------------------------------------------------------
__global__ __launch_bounds__(256) void pad_kernel(const float* __restrict__ x,
                                                  unsigned short* __restrict__ xt) {
  int blk = blockIdx.x;
  int b = blk / XT_H, ih = blk - b * XT_H;
  unsigned short* dst = xt + (size_t)blk * XT_ROW;
  int tid = threadIdx.x;

  if (ih == 0 || ih == XT_H - 1) {
    ushort8 z;
#pragma unroll
    for (int q = 0; q < 8; ++q) z[q] = 0;
    for (int i = tid; i < XT_ROW / 8; i += 256) ((ushort8*)dst)[i] = z;
    return;
  }

  __shared__ unsigned short lds[128 * 58];
  int h = ih - 1;
  const float* xb = x + (size_t)b * 128 * 3136 + (size_t)h * 56;
#pragma unroll 4
  for (int r = 0; r < 28; ++r) {
    int idx = r * 256 + tid;
    int c = idx / 56, w2 = idx - c * 56;
    lds[c * 58 + w2] = f2bf(xb[(size_t)c * 3136 + w2]);
  }
  __syncthreads();
#pragma unroll 4
  for (int r = 0; r < 29; ++r) {
    int idx = r * 256 + tid;
    int iw = idx >> 7, c = idx & 127;
    unsigned short v = 0;
    if (iw >= 1 && iw <= 56) v = lds[c * 58 + (iw - 1)];
    dst[idx] = v;
  }
}

// ---------------------------------------------------------------------------
// Kernel 3: implicit-im2col GEMM, single-phase K-loop.
// BM=128(o) x BN=256(n), BK=64, 8 waves (2M x 4N), wave tile 64x64.
// 3 LDS slots (48KB): compute kt from slot kt%3 while staging kt+2 into
// (kt+2)%3; ONE barrier per K-tile; counted vmcnt(6) never drains in steady
// state. Full 3-bit XOR swizzle (group ^= row&7): row stride 128B means the
// bank index depends only on the 16B group, so lanes must be spread over all
// 8 groups; write side pre-swizzles the per-lane GLOBAL source group while
// the LDS dest stays linear (global_load_lds requirement).
// ---------------------------------------------------------------------------
__device__ __forceinline__ constexpr int KB_OFF(int kt) {
  // xt element offset for K-tile kt: (kh*58+kw)*128 + (kt&1)*64
  int rr = kt >> 1;
  return ((rr / 3) * 58 + (rr % 3)) * 128 + (kt & 1) * 64;
}

#define ST_A(kts, sl2, r) \
  GLOAD_LDS16(pA[r] + (kts) * 64, smem + (sl2) * 24576 + (r) * 4096 + (w << 9))
#define ST_B(kts, sl2, r) \
  GLOAD_LDS16(pB[r] + KB_OFF(kts), smem + (sl2) * 24576 + 8192 + (r) * 4096 + (w << 9))

// row*128 bytes + swizzled 16B group; G = ks*4 + (lane>>4); group = G ^ (row&7)
#define LDS_FRAG(base, row, ks)                                            \
  (*(const short8*)((const char*)(base) + (row) * 128 +                    \
     (((((ks) << 2) + (lane >> 4)) ^ ((row) & 7)) << 4)))

__global__ __launch_bounds__(512, 2) void gemm_kernel(
    const unsigned short* __restrict__ Wt, const unsigned short* __restrict__ xt,
    const float* __restrict__ bias, float* __restrict__ out) {
  __shared__ __align__(1024) unsigned short smem[3 * 24576];  // 144 KiB

  // XCD swizzle (784 % 8 == 0): pair the 2 o-tiles of each n-tile on one XCD
  const int bid   = blockIdx.x;
  const int lid   = (bid & 7) * 98 + (bid >> 3);
  const int ntile = lid >> 1, otile = lid & 1;
  const int n0 = ntile << 8;   // *256
  const int o0 = otile << 7;   // *128

  const int tid  = threadIdx.x;
  const int w    = tid >> 6;
  const int lane = tid & 63;
  const int wm   = w >> 2;     // 0..1  (o)
  const int wn   = w & 3;      // 0..3  (n)

  // ---- staging source pointers (fixed; global group pre-swizzled) ----
  const unsigned short* pA[2];
  const unsigned short* pB[4];
#pragma unroll
  for (int r = 0; r < 2; ++r) {
    const int li  = r * 512 + tid;
    const int row = li >> 3;
    const int gs  = (li & 7) ^ (row & 7);
    pA[r] = Wt + (size_t)(o0 + row) * D_DIM + gs * 8;
  }
#pragma unroll
  for (int r = 0; r < 4; ++r) {
    const int li  = r * 512 + tid;
    const int row = li >> 3;
    const int gs  = (li & 7) ^ (row & 7);
    const int n_g = n0 + row;
    const int b   = n_g / 3136;
    const int s   = n_g - b * 3136;
    const int oh  = s / 56, ow = s - oh * 56;
    pB[r] = xt + (((size_t)b * XT_H + oh) * XT_H + ow) * 128 + gs * 8;
  }

  f32x4 acc[4][4] = {};

  // ---- prologue: stage K-tiles 0,1 into slots 0,1 ----
  ST_A(0, 0, 0); ST_A(0, 0, 1);
  ST_B(0, 0, 0); ST_B(0, 0, 1); ST_B(0, 0, 2); ST_B(0, 0, 3);
  ST_A(1, 1, 0); ST_A(1, 1, 1);
  ST_B(1, 1, 0); ST_B(1, 1, 1); ST_B(1, 1, 2); ST_B(1, 1, 3);
  asm volatile("s_waitcnt vmcnt(6)" ::: "memory");   // K-tile 0 landed
  __builtin_amdgcn_s_barrier();

#pragma unroll
  for (int kt = 0; kt < 18; ++kt) {
    const int sl  = kt % 3;
    const int kts = kt + 2;
    const int sl2 = kts % 3;
    const unsigned short* As = smem + sl * 24576;
    const unsigned short* Bs = smem + sl * 24576 + 8192;

    // ---- fragment reads (critical path first) ----
    short8 af[4][2], bf[4][2];
#pragma unroll
    for (int mi = 0; mi < 4; ++mi) {
      const int row = (wm << 6) + (mi << 4) + (lane & 15);
      af[mi][0] = LDS_FRAG(As, row, 0);
      af[mi][1] = LDS_FRAG(As, row, 1);
    }
#pragma unroll
    for (int ni = 0; ni < 4; ++ni) {
      const int row = (wn << 6) + (ni << 4) + (lane & 15);
      bf[ni][0] = LDS_FRAG(Bs, row, 0);
      bf[ni][1] = LDS_FRAG(Bs, row, 1);
    }
    // ---- stage kt+2 (slot freed at the last barrier) ----
    if (kts < 18) {
      ST_A(kts, sl2, 0); ST_A(kts, sl2, 1);
      ST_B(kts, sl2, 0); ST_B(kts, sl2, 1); ST_B(kts, sl2, 2); ST_B(kts, sl2, 3);
    }
    // ---- MFMA cluster (ks outer: 16 independent accs between dep pairs) ----
    __builtin_amdgcn_s_setprio(1);
#pragma unroll
    for (int ks = 0; ks < 2; ++ks)
#pragma unroll
      for (int mi = 0; mi < 4; ++mi)
#pragma unroll
        for (int ni = 0; ni < 4; ++ni)
          acc[mi][ni] = __builtin_amdgcn_mfma_f32_16x16x32_bf16(
              af[mi][ks], bf[ni][ks], acc[mi][ni], 0, 0, 0);
    __builtin_amdgcn_s_setprio(0);
    // ---- single sync point: kt+1's 6 loads landed; kt+2's 6 stay in flight
    if (kt < 16) asm volatile("s_waitcnt vmcnt(6)" ::: "memory");
    else         asm volatile("s_waitcnt vmcnt(0)" ::: "memory");
    __builtin_amdgcn_s_barrier();
  }

  // ---- epilogue: D row = o (lane>>4)*4+reg, col = n (lane&15) ----
  const int lr = (lane >> 4) << 2;
  const int lc = lane & 15;
#pragma unroll
  for (int ni = 0; ni < 4; ++ni) {
    const int ng = n0 + (wn << 6) + (ni << 4) + lc;
    const int b  = ng / 3136;
    const int s  = ng - b * 3136;
    float* op = out + (size_t)b * (O_DIM * 3136) + s;
#pragma unroll
    for (int mi = 0; mi < 4; ++mi) {
      const int og = o0 + (wm << 6) + (mi << 4) + lr;
#pragma unroll
      for (int r = 0; r < 4; ++r)
        op[(size_t)(og + r) * 3136] = acc[mi][ni][r] + 2.0f * bias[og + r];
    }
  }
}

// ---------------------------------------------------------------------------
extern "C" void kernel_launch(void* const* d_in, const int* in_sizes, int n_in,
                              void* d_out, int out_size, void* d_ws, size_t ws_size,
                              hipStream_t stream) {
  const float* x    = (const float*)d_in[0];
  const float* S1s  = (const float*)d_in[1];
  const float* U1s  = (const float*)d_in[2];
  const float* U2s  = (const float*)d_in[3];
  const float* S2s  = (const float*)d_in[4];
  const float* bias = (const float*)d_in[5];
  float* out = (float*)d_out;
  (void)ws_size;

  unsigned short* xt = (unsigned short*)d_ws;
  unsigned short* Wt = (unsigned short*)((char*)d_ws + (size_t)32 * XT_H * XT_ROW * 2);

  pad_kernel<<<dim3(32 * XT_H), dim3(256), 0, stream>>>(x, xt);
  wt_kernel<<<dim3(72), dim3(256), 0, stream>>>(S1s, U1s, U2s, S2s, Wt);
  gemm_kernel<<<dim3(784), dim3(512), 0, stream>>>(Wt, xt, bias, out);
}